// Round 1
// baseline (45.555 us; speedup 1.0000x reference)
//
#include <hip/hip_runtime.h>
#include <math.h>

#define BB 4
#define SS 4096
#define HH 2048
#define DD 3
#define KK 1365   // max(1, int(4096/3))

// ---------------- Kernel A: scores + loss partials ----------------
// One wave (64 lanes) per token. Each lane covers 32 floats (8 float4).
// Dot in f64 (deterministic, minimizes deviation from ref f32 GEMM),
// cast to f32, sigmoid in f32 to match reference rounding (ties at 1.0f!).
__global__ __launch_bounds__(256) void score_kernel(
    const float* __restrict__ hs, const float* __restrict__ theta,
    float* __restrict__ scores0, double* __restrict__ partials)
{
    const int wave = threadIdx.x >> 6;
    const int lane = threadIdx.x & 63;
    const long token = (long)blockIdx.x * 4 + wave;

    const float4* row = reinterpret_cast<const float4*>(hs + token * HH);
    const float4* t0p = reinterpret_cast<const float4*>(theta);
    const float4* t1p = reinterpret_cast<const float4*>(theta + HH);
    const float4* t2p = reinterpret_cast<const float4*>(theta + 2 * HH);

    double a0 = 0.0, a1 = 0.0, a2 = 0.0;
#pragma unroll
    for (int j = 0; j < HH / 256; ++j) {   // 8 iters
        const int v = j * 64 + lane;
        float4 h  = row[v];
        float4 x0 = t0p[v];
        float4 x1 = t1p[v];
        float4 x2 = t2p[v];
        a0 += (double)h.x * x0.x + (double)h.y * x0.y + (double)h.z * x0.z + (double)h.w * x0.w;
        a1 += (double)h.x * x1.x + (double)h.y * x1.y + (double)h.z * x1.z + (double)h.w * x1.w;
        a2 += (double)h.x * x2.x + (double)h.y * x2.y + (double)h.z * x2.z + (double)h.w * x2.w;
    }
#pragma unroll
    for (int off = 32; off; off >>= 1) {
        a0 += __shfl_down(a0, off);
        a1 += __shfl_down(a1, off);
        a2 += __shfl_down(a2, off);
    }

    __shared__ double wpart[4][DD];
    if (lane == 0) {
        float x0 = (float)a0, x1 = (float)a1, x2 = (float)a2;
        float s0 = 1.0f / (1.0f + expf(-x0));
        float s1 = 1.0f / (1.0f + expf(-x1));
        float s2 = 1.0f / (1.0f + expf(-x2));
        scores0[token] = s0;
        // loss uses sigmoid applied twice
        wpart[wave][0] = (double)(1.0f / (1.0f + expf(-s0)));
        wpart[wave][1] = (double)(1.0f / (1.0f + expf(-s1)));
        wpart[wave][2] = (double)(1.0f / (1.0f + expf(-s2)));
    }
    __syncthreads();
    if (threadIdx.x < DD) {
        const int d = threadIdx.x;
        partials[(long)blockIdx.x * DD + d] =
            wpart[0][d] + wpart[1][d] + wpart[2][d] + wpart[3][d];
    }
}

// ---------------- Kernel B: exact top-k per batch row ----------------
// Radix-select (4x8-bit, MSB first) on f32 bit patterns (all scores >= 0 so
// uint order == float order). Ties at the threshold value are resolved by
// lowest index via a block-wide prefix scan — matches jax.lax.top_k.
__global__ __launch_bounds__(1024) void topk_kernel(
    const float* __restrict__ scores0, float* __restrict__ out)
{
    const int tid  = threadIdx.x;
    const int lane = tid & 63;
    const int wid  = tid >> 6;
    const int b    = blockIdx.x;

    __shared__ __align__(16) unsigned su[SS];   // 16 KB
    __shared__ unsigned whist[16 * 256];        // per-wave histograms, 16 KB
    __shared__ unsigned wtot[4];
    __shared__ unsigned wsum[16];
    __shared__ unsigned sh_bin, sh_kk;

    const float* rowp = scores0 + b * SS;
    for (int i = tid; i < SS; i += 1024) su[i] = __float_as_uint(rowp[i]);

    unsigned prefix = 0, maskbits = 0;
    unsigned kk = KK;
    for (int pass = 0; pass < 4; ++pass) {
        const int shift = 24 - 8 * pass;
        for (int i = tid; i < 16 * 256; i += 1024) whist[i] = 0;
        __syncthreads();                                   // (1)
        for (int i = tid; i < SS; i += 1024) {
            unsigned u = su[i];
            if ((u & maskbits) == prefix)
                atomicAdd(&whist[(wid << 8) + ((u >> shift) & 255u)], 1u);
        }
        __syncthreads();                                   // (2)
        unsigned val = 0, s = 0;
        if (tid < 256) {
            for (int w = 0; w < 16; ++w) val += whist[(w << 8) + tid];
            // inclusive suffix scan within this wave (64 bins per wave)
            s = val;
#pragma unroll
            for (int off = 1; off < 64; off <<= 1) {
                unsigned t = __shfl_down(s, off);
                if (lane + off < 64) s += t;
            }
            if (lane == 0) wtot[wid] = s;   // total of this wave's bin range
        }
        __syncthreads();                                   // (3)
        if (tid < 256) {
            unsigned cge = s;
            for (int w = wid + 1; w < 4; ++w) cge += wtot[w];
            unsigned cgt = cge - val;       // count in strictly higher bins
            if (cgt < kk && cge >= kk) { sh_bin = (unsigned)tid; sh_kk = kk - cgt; }
        }
        __syncthreads();                                   // (4)
        prefix   |= (sh_bin << shift);
        maskbits |= (255u << shift);
        kk = sh_kk;
    }

    const unsigned vstar = prefix;   // k-th largest value (bit pattern)
    const unsigned rem   = kk;       // how many of the == group to take (lowest idx)

    // Each thread owns 4 contiguous elements.
    uint4 uu = reinterpret_cast<const uint4*>(su)[tid];
    const unsigned e0 = (uu.x == vstar), e1 = (uu.y == vstar),
                   e2 = (uu.z == vstar), e3 = (uu.w == vstar);
    const unsigned cnt = e0 + e1 + e2 + e3;

    // block exclusive scan of cnt over 1024 threads
    unsigned inc = cnt;
#pragma unroll
    for (int off = 1; off < 64; off <<= 1) {
        unsigned t = __shfl_up(inc, off);
        if (lane >= off) inc += t;
    }
    if (lane == 63) wsum[wid] = inc;
    __syncthreads();
    if (wid == 0) {
        unsigned wv = (lane < 16) ? wsum[lane] : 0;
#pragma unroll
        for (int off = 1; off < 16; off <<= 1) {
            unsigned t = __shfl_up(wv, off);
            if (lane >= off) wv += t;
        }
        if (lane < 16) wsum[lane] = wv;   // inclusive wave sums
    }
    __syncthreads();
    unsigned p = inc - cnt + (wid > 0 ? wsum[wid - 1] : 0);   // exclusive prefix

    const bool sel0 = (uu.x > vstar) || (e0 && p < rem); p += e0;
    const bool sel1 = (uu.y > vstar) || (e1 && p < rem); p += e1;
    const bool sel2 = (uu.z > vstar) || (e2 && p < rem); p += e2;
    const bool sel3 = (uu.w > vstar) || (e3 && p < rem);

    // ---- outputs (float32 flat): depth [B*S] | loss [1] | masks [D*B*S] ----
    const int base = tid * 4;
    float4 dv = make_float4(sel0 ? 3.0f : 1.0f, sel1 ? 3.0f : 1.0f,
                            sel2 ? 3.0f : 1.0f, sel3 ? 3.0f : 1.0f);
    reinterpret_cast<float4*>(out + (long)b * SS)[tid] = dv;

    float* m0 = out + (long)BB * SS + 1 + (long)b * SS;   // masks[0][b]
    float* m1 = m0 + (long)BB * SS;                        // masks[1][b]
    float* m2 = m1 + (long)BB * SS;                        // masks[2][b]
    // 16385-float offset is only 4B-aligned -> scalar stores
    m0[base + 0] = 1.0f; m0[base + 1] = 1.0f; m0[base + 2] = 1.0f; m0[base + 3] = 1.0f;
    m1[base + 0] = sel0 ? 1.0f : 0.0f; m1[base + 1] = sel1 ? 1.0f : 0.0f;
    m1[base + 2] = sel2 ? 1.0f : 0.0f; m1[base + 3] = sel3 ? 1.0f : 0.0f;
    m2[base + 0] = sel0 ? 1.0f : 0.0f; m2[base + 1] = sel1 ? 1.0f : 0.0f;
    m2[base + 2] = sel2 ? 1.0f : 0.0f; m2[base + 3] = sel3 ? 1.0f : 0.0f;
}

// ---------------- Kernel C: balancing loss ----------------
__global__ __launch_bounds__(256) void loss_kernel(
    const double* __restrict__ partials, float* __restrict__ out)
{
    const int tid = threadIdx.x;
    const int lane = tid & 63, wid = tid >> 6;
    double a0 = 0.0, a1 = 0.0, a2 = 0.0;
    for (int i = tid; i < 4096; i += 256) {
        a0 += partials[(long)i * DD + 0];
        a1 += partials[(long)i * DD + 1];
        a2 += partials[(long)i * DD + 2];
    }
#pragma unroll
    for (int off = 32; off; off >>= 1) {
        a0 += __shfl_down(a0, off);
        a1 += __shfl_down(a1, off);
        a2 += __shfl_down(a2, off);
    }
    __shared__ double sh[DD][4];
    if (lane == 0) { sh[0][wid] = a0; sh[1][wid] = a1; sh[2][wid] = a2; }
    __syncthreads();
    if (tid == 0) {
        const double n = (double)BB * SS;
        double p0 = (sh[0][0] + sh[0][1] + sh[0][2] + sh[0][3]) / n;
        double p1 = (sh[1][0] + sh[1][1] + sh[1][2] + sh[1][3]) / n;
        double p2 = (sh[2][0] + sh[2][1] + sh[2][2] + sh[2][3]) / n;
        const double t = 1.0 / 3.0;
        double loss = (t * (log(t) - log(p0)) +
                       t * (log(t) - log(p1)) +
                       t * (log(t) - log(p2))) / 3.0;
        out[(long)BB * SS] = (float)loss;
    }
}

extern "C" void kernel_launch(void* const* d_in, const int* in_sizes, int n_in,
                              void* d_out, int out_size, void* d_ws, size_t ws_size,
                              hipStream_t stream) {
    const float* hs    = (const float*)d_in[0];
    const float* theta = (const float*)d_in[1];
    float* out = (float*)d_out;

    float*  scores0  = (float*)d_ws;                                  // 64 KB
    double* partials = (double*)((char*)d_ws + (size_t)BB * SS * 4);  // 96 KB

    score_kernel<<<dim3(BB * SS / 4), dim3(256), 0, stream>>>(hs, theta, scores0, partials);
    topk_kernel <<<dim3(BB),          dim3(1024), 0, stream>>>(scores0, out);
    loss_kernel <<<dim3(1),           dim3(256), 0, stream>>>(partials, out);
}

// Round 2
// 31.394 us; speedup vs baseline: 1.4511x; 1.4511x over previous
//
#include <hip/hip_runtime.h>
#include <math.h>

#define BB 4
#define SS 4096
#define HH 2048
#define DD 3
#define KK 1365            // max(1, int(4096/3))
#define ONEBITS 0x3f800000u

// ---------------- Kernel A: scores + loss partials + m0 ones ----------------
// One wave (64 lanes) per token. Dot in f64 (deterministic, matches ref
// selection exactly — verified absmax 0.0), cast to f32, sigmoid in f32.
__global__ __launch_bounds__(256) void score_kernel(
    const float* __restrict__ hs, const float* __restrict__ theta,
    float* __restrict__ scores0, double* __restrict__ partials,
    float* __restrict__ m0)
{
    // masks[0] is all-ones, data-independent: spread the 64 KB write here.
    const long gid = (long)blockIdx.x * 256 + threadIdx.x;
    if (gid < (long)BB * SS) m0[gid] = 1.0f;

    const int wave = threadIdx.x >> 6;
    const int lane = threadIdx.x & 63;
    const long token = (long)blockIdx.x * 4 + wave;

    const float4* row = reinterpret_cast<const float4*>(hs + token * HH);
    const float4* t0p = reinterpret_cast<const float4*>(theta);
    const float4* t1p = reinterpret_cast<const float4*>(theta + HH);
    const float4* t2p = reinterpret_cast<const float4*>(theta + 2 * HH);

    double a0 = 0.0, a1 = 0.0, a2 = 0.0;
#pragma unroll
    for (int j = 0; j < HH / 256; ++j) {   // 8 iters
        const int v = j * 64 + lane;
        float4 h  = row[v];
        float4 x0 = t0p[v];
        float4 x1 = t1p[v];
        float4 x2 = t2p[v];
        a0 += (double)h.x * x0.x + (double)h.y * x0.y + (double)h.z * x0.z + (double)h.w * x0.w;
        a1 += (double)h.x * x1.x + (double)h.y * x1.y + (double)h.z * x1.z + (double)h.w * x1.w;
        a2 += (double)h.x * x2.x + (double)h.y * x2.y + (double)h.z * x2.z + (double)h.w * x2.w;
    }
#pragma unroll
    for (int off = 32; off; off >>= 1) {
        a0 += __shfl_down(a0, off);
        a1 += __shfl_down(a1, off);
        a2 += __shfl_down(a2, off);
    }

    __shared__ double wpart[4][DD];
    if (lane == 0) {
        float x0 = (float)a0, x1 = (float)a1, x2 = (float)a2;
        float s0 = 1.0f / (1.0f + expf(-x0));
        float s1 = 1.0f / (1.0f + expf(-x1));
        float s2 = 1.0f / (1.0f + expf(-x2));
        scores0[token] = s0;
        wpart[wave][0] = (double)(1.0f / (1.0f + expf(-s0)));
        wpart[wave][1] = (double)(1.0f / (1.0f + expf(-s1)));
        wpart[wave][2] = (double)(1.0f / (1.0f + expf(-s2)));
    }
    __syncthreads();
    if (threadIdx.x < DD) {
        const int d = threadIdx.x;
        partials[(long)blockIdx.x * DD + d] =
            wpart[0][d] + wpart[1][d] + wpart[2][d] + wpart[3][d];
    }
}

// ---------------- Kernel B: selection (12 blocks) + loss (block 12) ---------
// Blocks 0..11: (row b = blk/3, plane = blk%3 of {depth, m1, m2}).
// Fast path: sigmoid <= 1.0f, so if count(score==1.0f) >= k the k-th largest
// is exactly 1.0f and selection = first k indices equal to 1.0f (one scan).
// Fallback: exact 4x8-bit radix select (verified last round), block-uniform.
__global__ __launch_bounds__(1024) void select_kernel(
    const float* __restrict__ scores0, const double* __restrict__ partials,
    float* __restrict__ out)
{
    const int tid  = threadIdx.x;
    const int lane = tid & 63;
    const int wid  = tid >> 6;
    const int blk  = blockIdx.x;

    if (blk == 12) {   // ---- balancing loss ----
        double a0 = 0.0, a1 = 0.0, a2 = 0.0;
        for (int i = tid; i < 4096; i += 1024) {
            a0 += partials[(long)i * DD + 0];
            a1 += partials[(long)i * DD + 1];
            a2 += partials[(long)i * DD + 2];
        }
#pragma unroll
        for (int off = 32; off; off >>= 1) {
            a0 += __shfl_down(a0, off);
            a1 += __shfl_down(a1, off);
            a2 += __shfl_down(a2, off);
        }
        __shared__ double shl[DD][16];
        if (lane == 0) { shl[0][wid] = a0; shl[1][wid] = a1; shl[2][wid] = a2; }
        __syncthreads();
        if (tid == 0) {
            double p0 = 0, p1 = 0, p2 = 0;
            for (int w = 0; w < 16; ++w) { p0 += shl[0][w]; p1 += shl[1][w]; p2 += shl[2][w]; }
            const double n = (double)BB * SS;
            p0 /= n; p1 /= n; p2 /= n;
            const double t = 1.0 / 3.0;
            out[(long)BB * SS] = (float)((t * (log(t) - log(p0)) +
                                          t * (log(t) - log(p1)) +
                                          t * (log(t) - log(p2))) / 3.0);
        }
        return;
    }

    const int b = blk / 3, plane = blk % 3;
    const float* rowp = scores0 + (long)b * SS;

    __shared__ unsigned wsum[16];
    __shared__ __align__(16) unsigned su[SS];   // fallback only
    __shared__ unsigned whist[16 * 256];        // fallback only
    __shared__ unsigned wtot[4];
    __shared__ unsigned sbin, skk;

    uint4 uu = reinterpret_cast<const uint4*>(rowp)[tid];

    unsigned vstar = ONEBITS;
    unsigned e0 = (uu.x == vstar), e1 = (uu.y == vstar),
             e2 = (uu.z == vstar), e3 = (uu.w == vstar);
    unsigned cnt = e0 + e1 + e2 + e3;

    // block exclusive scan of cnt (also yields block total)
    unsigned inc = cnt;
#pragma unroll
    for (int off = 1; off < 64; off <<= 1) {
        unsigned t = __shfl_up(inc, off);
        if (lane >= off) inc += t;
    }
    if (lane == 63) wsum[wid] = inc;
    __syncthreads();
    if (wid == 0) {
        unsigned wv = (lane < 16) ? wsum[lane] : 0;
#pragma unroll
        for (int off = 1; off < 16; off <<= 1) {
            unsigned t = __shfl_up(wv, off);
            if (lane >= off) wv += t;
        }
        if (lane < 16) wsum[lane] = wv;
    }
    __syncthreads();
    unsigned p     = inc - cnt + (wid > 0 ? wsum[wid - 1] : 0);
    unsigned total = wsum[15];
    unsigned rem   = KK;

    if (total < KK) {   // ---- block-uniform fallback: exact radix select ----
        for (int i = tid; i < SS; i += 1024) su[i] = __float_as_uint(rowp[i]);
        unsigned prefix = 0, maskbits = 0, kk = KK;
        for (int pass = 0; pass < 4; ++pass) {
            const int shift = 24 - 8 * pass;
            for (int i = tid; i < 16 * 256; i += 1024) whist[i] = 0;
            __syncthreads();
            for (int i = tid; i < SS; i += 1024) {
                unsigned u = su[i];
                if ((u & maskbits) == prefix)
                    atomicAdd(&whist[(wid << 8) + ((u >> shift) & 255u)], 1u);
            }
            __syncthreads();
            unsigned val = 0, s = 0;
            if (tid < 256) {
                for (int w = 0; w < 16; ++w) val += whist[(w << 8) + tid];
                s = val;
#pragma unroll
                for (int off = 1; off < 64; off <<= 1) {
                    unsigned t = __shfl_down(s, off);
                    if (lane + off < 64) s += t;
                }
                if (lane == 0) wtot[wid] = s;
            }
            __syncthreads();
            if (tid < 256) {
                unsigned cge = s;
                for (int w = wid + 1; w < 4; ++w) cge += wtot[w];
                unsigned cgt = cge - val;
                if (cgt < kk && cge >= kk) { sbin = (unsigned)tid; skk = kk - cgt; }
            }
            __syncthreads();
            prefix   |= (sbin << shift);
            maskbits |= (255u << shift);
            kk = skk;
        }
        vstar = prefix;
        rem   = kk;
        // recompute equality flags and redo the scan for the new vstar
        e0 = (uu.x == vstar); e1 = (uu.y == vstar);
        e2 = (uu.z == vstar); e3 = (uu.w == vstar);
        cnt = e0 + e1 + e2 + e3;
        inc = cnt;
#pragma unroll
        for (int off = 1; off < 64; off <<= 1) {
            unsigned t = __shfl_up(inc, off);
            if (lane >= off) inc += t;
        }
        __syncthreads();   // protect wsum reuse
        if (lane == 63) wsum[wid] = inc;
        __syncthreads();
        if (wid == 0) {
            unsigned wv = (lane < 16) ? wsum[lane] : 0;
#pragma unroll
            for (int off = 1; off < 16; off <<= 1) {
                unsigned t = __shfl_up(wv, off);
                if (lane >= off) wv += t;
            }
            if (lane < 16) wsum[lane] = wv;
        }
        __syncthreads();
        p = inc - cnt + (wid > 0 ? wsum[wid - 1] : 0);
    }

    // selection: strictly-greater always in; ties by lowest index
    const bool sel0 = (uu.x > vstar) || (e0 && p < rem); p += e0;
    const bool sel1 = (uu.y > vstar) || (e1 && p < rem); p += e1;
    const bool sel2 = (uu.z > vstar) || (e2 && p < rem); p += e2;
    const bool sel3 = (uu.w > vstar) || (e3 && p < rem);

    if (plane == 0) {
        float4 dv = make_float4(sel0 ? 3.0f : 1.0f, sel1 ? 3.0f : 1.0f,
                                sel2 ? 3.0f : 1.0f, sel3 ? 3.0f : 1.0f);
        reinterpret_cast<float4*>(out + (long)b * SS)[tid] = dv;
    } else {
        // masks base is out + B*S + 1 (odd float offset -> scalar stores)
        float* m = out + (long)BB * SS + 1 + (long)plane * BB * SS + (long)b * SS;
        const int base = tid * 4;
        m[base + 0] = sel0 ? 1.0f : 0.0f;
        m[base + 1] = sel1 ? 1.0f : 0.0f;
        m[base + 2] = sel2 ? 1.0f : 0.0f;
        m[base + 3] = sel3 ? 1.0f : 0.0f;
    }
}

extern "C" void kernel_launch(void* const* d_in, const int* in_sizes, int n_in,
                              void* d_out, int out_size, void* d_ws, size_t ws_size,
                              hipStream_t stream) {
    const float* hs    = (const float*)d_in[0];
    const float* theta = (const float*)d_in[1];
    float* out = (float*)d_out;

    float*  scores0  = (float*)d_ws;                                  // 64 KB
    double* partials = (double*)((char*)d_ws + (size_t)BB * SS * 4);  // 96 KB
    float*  m0       = out + (long)BB * SS + 1;                       // masks[0]

    score_kernel <<<dim3(BB * SS / 4), dim3(256),  0, stream>>>(hs, theta, scores0, partials, m0);
    select_kernel<<<dim3(13),          dim3(1024), 0, stream>>>(scores0, partials, out);
}